// Round 1
// baseline (857.658 us; speedup 1.0000x reference)
//
#include <hip/hip_runtime.h>
#include <hip/hip_bf16.h>
#include <cstdint>

#define T_TOK 2048
#define HDIM  2048
#define IDIM  8192
#define NEXP  8

typedef short s16x8 __attribute__((ext_vector_type(8)));
typedef float f32x4 __attribute__((ext_vector_type(4)));

__device__ __forceinline__ unsigned short f2b(float f) {
    union { float f; unsigned u; } c; c.f = f;
    unsigned r = (c.u + 0x7fffu + ((c.u >> 16) & 1u)) >> 16;
    return (unsigned short)r;
}

__device__ __forceinline__ float gelu_tanh(float v) {
    float u = 0.7978845608028654f * (v + 0.044715f * v * v * v);
    return 0.5f * v * (1.0f + tanhf(u));
}

// ---------------- K1: gate (logits fp32, softmax, top-2) + cast x -> bf16 ----
__global__ __launch_bounds__(256) void k_gate(
    const float* __restrict__ x, const float* __restrict__ gw,
    const float* __restrict__ gb, const float* __restrict__ alpha,
    unsigned short* __restrict__ xb, int* __restrict__ counts,
    int* __restrict__ top_e, float* __restrict__ top_g)
{
    const int wave = threadIdx.x >> 6;
    const int lane = threadIdx.x & 63;
    const int t = blockIdx.x * 4 + wave;
    if (t >= T_TOK) return;

    float acc[8];
    #pragma unroll
    for (int e = 0; e < 8; e++) acc[e] = 0.f;

    const float* xrow = x + (size_t)t * HDIM;
    unsigned short* xbrow = xb + (size_t)t * HDIM;

    #pragma unroll
    for (int c = 0; c < 8; c++) {
        const int h0 = c * 256 + lane * 4;
        const float4 xv = *reinterpret_cast<const float4*>(xrow + h0);
        ushort4 u;
        u.x = f2b(xv.x); u.y = f2b(xv.y); u.z = f2b(xv.z); u.w = f2b(xv.w);
        *reinterpret_cast<ushort4*>(xbrow + h0) = u;
        const float xs[4] = {xv.x, xv.y, xv.z, xv.w};
        #pragma unroll
        for (int r = 0; r < 4; r++) {
            const float4 g0 = *reinterpret_cast<const float4*>(gw + (size_t)(h0 + r) * 8);
            const float4 g1 = *reinterpret_cast<const float4*>(gw + (size_t)(h0 + r) * 8 + 4);
            acc[0] += xs[r] * g0.x; acc[1] += xs[r] * g0.y;
            acc[2] += xs[r] * g0.z; acc[3] += xs[r] * g0.w;
            acc[4] += xs[r] * g1.x; acc[5] += xs[r] * g1.y;
            acc[6] += xs[r] * g1.z; acc[7] += xs[r] * g1.w;
        }
    }
    #pragma unroll
    for (int e = 0; e < 8; e++) {
        #pragma unroll
        for (int off = 32; off > 0; off >>= 1)
            acc[e] += __shfl_xor(acc[e], off);
        acc[e] += gb[e];
    }
    // softmax + top-2 (computed redundantly on every lane)
    float m = acc[0];
    #pragma unroll
    for (int e = 1; e < 8; e++) m = fmaxf(m, acc[e]);
    float Z = 0.f;
    #pragma unroll
    for (int e = 0; e < 8; e++) Z += expf(acc[e] - m);
    int e0 = 0; float b0 = acc[0];
    #pragma unroll
    for (int e = 1; e < 8; e++) if (acc[e] > b0) { b0 = acc[e]; e0 = e; }
    int e1 = -1; float b1 = -1e30f;
    #pragma unroll
    for (int e = 0; e < 8; e++) if (e != e0 && acc[e] > b1) { b1 = acc[e]; e1 = e; }

    if (lane == 0) {
        const float s0 = expf(b0 - m) / Z * alpha[e0];
        const float s1 = expf(b1 - m) / Z * alpha[e1];
        top_e[2 * t]     = e0; top_e[2 * t + 1] = e1;
        top_g[2 * t]     = s0; top_g[2 * t + 1] = s1;
        atomicAdd(&counts[e0], 1);
        atomicAdd(&counts[e1], 1);
    }
}

// ---------------- K2: exclusive scan of 8 counts -----------------------------
__global__ void k_scan(const int* __restrict__ counts, int* __restrict__ offsets,
                       int* __restrict__ cursors)
{
    if (threadIdx.x == 0) {
        int off = 0;
        for (int e = 0; e < NEXP; e++) {
            offsets[e] = off; cursors[e] = off; off += counts[e];
        }
    }
}

// ---------------- K3: append tokens to per-expert compact slot lists ---------
__global__ __launch_bounds__(256) void k_append(
    const int* __restrict__ top_e, const float* __restrict__ top_g,
    int* __restrict__ cursors, int* __restrict__ slot_token,
    float* __restrict__ slot_gate, int* __restrict__ tok2slot)
{
    const int t = blockIdx.x * 256 + threadIdx.x;
    if (t >= T_TOK) return;
    #pragma unroll
    for (int k = 0; k < 2; k++) {
        const int e = top_e[2 * t + k];
        const int slot = atomicAdd(&cursors[e], 1);
        slot_token[slot] = t;
        slot_gate[slot]  = top_g[2 * t + k];
        tok2slot[2 * t + k] = slot;
    }
}

// ---------------- K4: fc1 GEMM (gathered tokens) + bias + GELU -> h1 bf16 ----
__global__ __launch_bounds__(256) void k_fc1(
    const unsigned short* __restrict__ xb, const float* __restrict__ w1,
    const float* __restrict__ b1, const int* __restrict__ counts,
    const int* __restrict__ offsets, const int* __restrict__ slot_token,
    unsigned short* __restrict__ h1)
{
    const int e   = blockIdx.z;
    const int cnt = counts[e];
    const int m0  = blockIdx.y * 128;
    if (m0 >= cnt) return;
    const int moff = offsets[e];
    const int n0   = blockIdx.x * 128;

    __shared__ short As[128 * 40];
    __shared__ short Bs[128 * 40];
    __shared__ int row_tok[128];

    const int tid = threadIdx.x;
    if (tid < 128)
        row_tok[tid] = (m0 + tid < cnt) ? slot_token[moff + m0 + tid] : 0;
    __syncthreads();

    const int wave = tid >> 6, lane = tid & 63;
    const int wm = wave >> 1, wn = wave & 1;
    const int lo = lane & 15, hi = lane >> 4;

    f32x4 acc[4][4];
    #pragma unroll
    for (int i = 0; i < 4; i++)
        #pragma unroll
        for (int j = 0; j < 4; j++) acc[i][j] = (f32x4)0.f;

    const float* wbase = w1 + (size_t)e * HDIM * IDIM + n0;

    for (int kk = 0; kk < HDIM; kk += 32) {
        #pragma unroll
        for (int it = 0; it < 2; it++) {
            const int id = tid + it * 256;
            const int row = id >> 2, kg = id & 3;
            const int tok = row_tok[row];
            const s16x8 av = *reinterpret_cast<const s16x8*>(
                xb + (size_t)tok * HDIM + kk + kg * 8);
            *reinterpret_cast<s16x8*>(&As[row * 40 + kg * 8]) = av;
        }
        #pragma unroll
        for (int it = 0; it < 2; it++) {
            const int id = tid + it * 256;
            const int n = id & 127, kg = id >> 7;
            s16x8 bv;
            #pragma unroll
            for (int j = 0; j < 8; j++) {
                const float f = wbase[(size_t)(kk + kg * 8 + j) * IDIM + n];
                bv[j] = (short)f2b(f);
            }
            *reinterpret_cast<s16x8*>(&Bs[n * 40 + kg * 8]) = bv;
        }
        __syncthreads();
        s16x8 af[4], bfr[4];
        #pragma unroll
        for (int i = 0; i < 4; i++)
            af[i] = *reinterpret_cast<const s16x8*>(&As[(wm * 64 + i * 16 + lo) * 40 + hi * 8]);
        #pragma unroll
        for (int j = 0; j < 4; j++)
            bfr[j] = *reinterpret_cast<const s16x8*>(&Bs[(wn * 64 + j * 16 + lo) * 40 + hi * 8]);
        #pragma unroll
        for (int i = 0; i < 4; i++)
            #pragma unroll
            for (int j = 0; j < 4; j++)
                acc[i][j] = __builtin_amdgcn_mfma_f32_16x16x32_bf16(af[i], bfr[j], acc[i][j], 0, 0, 0);
        __syncthreads();
    }

    #pragma unroll
    for (int i = 0; i < 4; i++) {
        #pragma unroll
        for (int r = 0; r < 4; r++) {
            const int row = wm * 64 + i * 16 + hi * 4 + r;
            if (m0 + row >= cnt) continue;
            const size_t orow = (size_t)(moff + m0 + row) * IDIM;
            #pragma unroll
            for (int j = 0; j < 4; j++) {
                const int col = n0 + wn * 64 + j * 16 + lo;
                const float v = acc[i][j][r] + b1[e * IDIM + col];
                h1[orow + col] = f2b(gelu_tanh(v));
            }
        }
    }
}

// ---------------- K5: fc2 GEMM + gate*(acc + bias) -> per-slot rows ----------
__global__ __launch_bounds__(256) void k_fc2(
    const unsigned short* __restrict__ h1, const float* __restrict__ w2,
    const float* __restrict__ b2, const int* __restrict__ counts,
    const int* __restrict__ offsets, const float* __restrict__ slot_gate,
    float* __restrict__ outslot)
{
    const int e   = blockIdx.z;
    const int cnt = counts[e];
    const int m0  = blockIdx.y * 128;
    if (m0 >= cnt) return;
    const int moff = offsets[e];
    const int n0   = blockIdx.x * 128;
    const int slot0 = moff + m0;

    __shared__ short As[128 * 40];
    __shared__ short Bs[128 * 40];
    __shared__ float grow[128];

    const int tid = threadIdx.x;
    if (tid < 128)
        grow[tid] = (m0 + tid < cnt) ? slot_gate[slot0 + tid] : 0.f;

    const int wave = tid >> 6, lane = tid & 63;
    const int wm = wave >> 1, wn = wave & 1;
    const int lo = lane & 15, hi = lane >> 4;

    f32x4 acc[4][4];
    #pragma unroll
    for (int i = 0; i < 4; i++)
        #pragma unroll
        for (int j = 0; j < 4; j++) acc[i][j] = (f32x4)0.f;

    const float* wbase = w2 + (size_t)e * IDIM * HDIM + n0;

    for (int kk = 0; kk < IDIM; kk += 32) {
        #pragma unroll
        for (int it = 0; it < 2; it++) {
            const int id = tid + it * 256;
            const int row = id >> 2, kg = id & 3;
            const s16x8 av = *reinterpret_cast<const s16x8*>(
                h1 + (size_t)(slot0 + row) * IDIM + kk + kg * 8);
            *reinterpret_cast<s16x8*>(&As[row * 40 + kg * 8]) = av;
        }
        #pragma unroll
        for (int it = 0; it < 2; it++) {
            const int id = tid + it * 256;
            const int n = id & 127, kg = id >> 7;
            s16x8 bv;
            #pragma unroll
            for (int j = 0; j < 8; j++) {
                const float f = wbase[(size_t)(kk + kg * 8 + j) * HDIM + n];
                bv[j] = (short)f2b(f);
            }
            *reinterpret_cast<s16x8*>(&Bs[n * 40 + kg * 8]) = bv;
        }
        __syncthreads();
        s16x8 af[4], bfr[4];
        #pragma unroll
        for (int i = 0; i < 4; i++)
            af[i] = *reinterpret_cast<const s16x8*>(&As[(wm * 64 + i * 16 + lo) * 40 + hi * 8]);
        #pragma unroll
        for (int j = 0; j < 4; j++)
            bfr[j] = *reinterpret_cast<const s16x8*>(&Bs[(wn * 64 + j * 16 + lo) * 40 + hi * 8]);
        #pragma unroll
        for (int i = 0; i < 4; i++)
            #pragma unroll
            for (int j = 0; j < 4; j++)
                acc[i][j] = __builtin_amdgcn_mfma_f32_16x16x32_bf16(af[i], bfr[j], acc[i][j], 0, 0, 0);
        __syncthreads();
    }

    #pragma unroll
    for (int i = 0; i < 4; i++) {
        #pragma unroll
        for (int r = 0; r < 4; r++) {
            const int row = wm * 64 + i * 16 + hi * 4 + r;
            if (m0 + row >= cnt) continue;
            const float g = grow[row];
            const size_t orow = (size_t)(slot0 + row) * HDIM;
            #pragma unroll
            for (int j = 0; j < 4; j++) {
                const int col = n0 + wn * 64 + j * 16 + lo;
                outslot[orow + col] = g * (acc[i][j][r] + b2[e * HDIM + col]);
            }
        }
    }
}

// ---------------- K6: combine the two slot rows per token --------------------
__global__ __launch_bounds__(256) void k_combine(
    const float* __restrict__ outslot, const int* __restrict__ tok2slot,
    float* __restrict__ out)
{
    const int t = blockIdx.x;
    const int sA = tok2slot[2 * t], sB = tok2slot[2 * t + 1];
    const float* ra = outslot + (size_t)sA * HDIM;
    const float* rb = outslot + (size_t)sB * HDIM;
    float* ro = out + (size_t)t * HDIM;
    #pragma unroll
    for (int c = 0; c < 2; c++) {
        const int i = c * 1024 + threadIdx.x * 4;
        const float4 a = *reinterpret_cast<const float4*>(ra + i);
        const float4 b = *reinterpret_cast<const float4*>(rb + i);
        float4 o; o.x = a.x + b.x; o.y = a.y + b.y; o.z = a.z + b.z; o.w = a.w + b.w;
        *reinterpret_cast<float4*>(ro + i) = o;
    }
}

extern "C" void kernel_launch(void* const* d_in, const int* in_sizes, int n_in,
                              void* d_out, int out_size, void* d_ws, size_t ws_size,
                              hipStream_t stream)
{
    const float* x  = (const float*)d_in[0];
    const float* gw = (const float*)d_in[1];
    const float* gb = (const float*)d_in[2];
    const float* w1 = (const float*)d_in[3];
    const float* b1 = (const float*)d_in[4];
    const float* w2 = (const float*)d_in[5];
    const float* b2 = (const float*)d_in[6];
    const float* al = (const float*)d_in[7];
    float* out = (float*)d_out;

    char* ws = (char*)d_ws;
    unsigned short* xb = (unsigned short*)ws;                    // 8,388,608 B
    unsigned short* h1 = (unsigned short*)(ws + 8388608);        // 67,108,864 B
    float* outslot     = (float*)(ws + 75497472);                // 33,554,432 B
    char* meta = ws + 109051904;
    int* counts     = (int*)meta;
    int* offsets    = (int*)(meta + 32);
    int* cursors    = (int*)(meta + 64);
    int* slot_token = (int*)(meta + 256);
    int* tok2slot   = (int*)(meta + 256 + 16384);
    int* top_e      = (int*)(meta + 256 + 32768);
    float* slot_gate= (float*)(meta + 256 + 49152);
    float* top_g    = (float*)(meta + 256 + 65536);

    hipMemsetAsync(counts, 0, 32, stream);
    k_gate<<<dim3(T_TOK / 4), dim3(256), 0, stream>>>(x, gw, gb, al, xb, counts, top_e, top_g);
    k_scan<<<dim3(1), dim3(64), 0, stream>>>(counts, offsets, cursors);
    k_append<<<dim3(T_TOK / 256), dim3(256), 0, stream>>>(top_e, top_g, cursors,
                                                          slot_token, slot_gate, tok2slot);
    k_fc1<<<dim3(IDIM / 128, T_TOK / 128, NEXP), dim3(256), 0, stream>>>(
        xb, w1, b1, counts, offsets, slot_token, h1);
    k_fc2<<<dim3(HDIM / 128, T_TOK / 128, NEXP), dim3(256), 0, stream>>>(
        h1, w2, b2, counts, offsets, slot_gate, outslot);
    k_combine<<<dim3(T_TOK), dim3(256), 0, stream>>>(outslot, tok2slot, out);
}